// Round 1
// baseline (603.257 us; speedup 1.0000x reference)
//
#include <hip/hip_runtime.h>

// Problem constants (module hard-codes these; B from reference file).
constexpr int BATCH = 1048576;
constexpr int H = 20;   // hidden
// IN = 2, A = 3 hard-coded below.

__device__ __forceinline__ float sigmoidf_stable(float z) {
    // matches jax.nn.sigmoid / scipy expit numerics
    if (z >= 0.0f) {
        float e = expf(-z);
        return 1.0f / (1.0f + e);
    } else {
        float e = expf(z);
        return e / (1.0f + e);
    }
}

__global__ __launch_bounds__(256) void lstm_coord_kernel(
    const float* __restrict__ x,
    const float* __restrict__ hx,
    const float* __restrict__ cx,
    const float* __restrict__ u,
    const float* __restrict__ W_ih,
    const float* __restrict__ W_hh,
    const float* __restrict__ b_ih,
    const float* __restrict__ b_hh,
    const float* __restrict__ W_dec,
    const float* __restrict__ b_dec,
    float* __restrict__ out)
{
    // ---- stage weights in LDS (uniform-address broadcast reads later) ----
    __shared__ float sWih[80 * 2];
    __shared__ float sWhh[80 * H];
    __shared__ float sB[80];        // b_ih + b_hh fused
    __shared__ float sWdec[3 * H];
    __shared__ float sBdec[3];

    const int t = threadIdx.x;
    for (int i = t; i < 160; i += 256)  sWih[i] = W_ih[i];
    for (int i = t; i < 1600; i += 256) sWhh[i] = W_hh[i];
    if (t < 80) sB[t] = b_ih[t] + b_hh[t];
    if (t < 60) sWdec[t] = W_dec[t];
    if (t < 3)  sBdec[t] = b_dec[t];
    __syncthreads();

    const int b = blockIdx.x * 256 + t;

    // ---- per-element loads (vectorized: rows are 16B-aligned) ----
    const float x0 = x[2 * b];
    const float x1 = x[2 * b + 1];
    float hv[H], cv[H];
#pragma unroll
    for (int k4 = 0; k4 < 5; ++k4) {
        float4 hh = *reinterpret_cast<const float4*>(hx + (size_t)b * H + 4 * k4);
        hv[4 * k4 + 0] = hh.x; hv[4 * k4 + 1] = hh.y;
        hv[4 * k4 + 2] = hh.z; hv[4 * k4 + 3] = hh.w;
        float4 cc = *reinterpret_cast<const float4*>(cx + (size_t)b * H + 4 * k4);
        cv[4 * k4 + 0] = cc.x; cv[4 * k4 + 1] = cc.y;
        cv[4 * k4 + 2] = cc.z; cv[4 * k4 + 3] = cc.w;
    }
    const float uv = u[b];

    // ---- LSTM cell + fused decode accumulation ----
    float l0 = sBdec[0], l1 = sBdec[1], l2 = sBdec[2];
    float hq_arr[H];
#pragma unroll
    for (int q = 0; q < H; ++q) {
        float gi = sB[q]      + x0 * sWih[2 * q]          + x1 * sWih[2 * q + 1];
        float gf = sB[20 + q] + x0 * sWih[2 * (20 + q)]   + x1 * sWih[2 * (20 + q) + 1];
        float gg = sB[40 + q] + x0 * sWih[2 * (40 + q)]   + x1 * sWih[2 * (40 + q) + 1];
        float go = sB[60 + q] + x0 * sWih[2 * (60 + q)]   + x1 * sWih[2 * (60 + q) + 1];
#pragma unroll
        for (int k = 0; k < H; ++k) {
            const float hk = hv[k];
            gi += hk * sWhh[(q)      * H + k];
            gf += hk * sWhh[(20 + q) * H + k];
            gg += hk * sWhh[(40 + q) * H + k];
            go += hk * sWhh[(60 + q) * H + k];
        }
        gi = sigmoidf_stable(gi);
        gf = sigmoidf_stable(gf);
        gg = tanhf(gg);
        go = sigmoidf_stable(go);
        const float cq = gf * cv[q] + gi * gg;
        const float hq = go * tanhf(cq);
        cv[q] = cq;
        hq_arr[q] = hq;
        l0 += hq * sWdec[q];
        l1 += hq * sWdec[20 + q];
        l2 += hq * sWdec[40 + q];
    }

    // ---- log_softmax + inverse-CDF sample (mirror reference op order) ----
    const float m = fmaxf(fmaxf(l0, l1), l2);
    const float s = expf(l0 - m) + expf(l1 - m) + expf(l2 - m);
    const float lse = m + logf(s);
    const float lp0 = l0 - lse, lp1 = l1 - lse, lp2 = l2 - lse;
    const float p0 = expf(lp0), p1 = expf(lp1), p2 = expf(lp2);
    const float c0 = p0;
    const float c1 = c0 + p1;
    const float c2 = c1 + p2;
    int act = (int)(c0 < uv) + (int)(c1 < uv) + (int)(c2 < uv);
    act = act > 2 ? 2 : act;
    const float slp = (act == 0) ? lp0 : ((act == 1) ? lp1 : lp2);

    // ---- outputs: [action(B) | slp(B) | h(B*20) | c(B*20)] as float32 ----
    out[b] = (float)act;
    out[(size_t)BATCH + b] = slp;
    float* hout = out + 2 * (size_t)BATCH;
    float* cout_ = out + 2 * (size_t)BATCH + (size_t)H * BATCH;
#pragma unroll
    for (int k4 = 0; k4 < 5; ++k4) {
        float4 hh = make_float4(hq_arr[4 * k4 + 0], hq_arr[4 * k4 + 1],
                                hq_arr[4 * k4 + 2], hq_arr[4 * k4 + 3]);
        *reinterpret_cast<float4*>(hout + (size_t)b * H + 4 * k4) = hh;
        float4 cc = make_float4(cv[4 * k4 + 0], cv[4 * k4 + 1],
                                cv[4 * k4 + 2], cv[4 * k4 + 3]);
        *reinterpret_cast<float4*>(cout_ + (size_t)b * H + 4 * k4) = cc;
    }
}

extern "C" void kernel_launch(void* const* d_in, const int* in_sizes, int n_in,
                              void* d_out, int out_size, void* d_ws, size_t ws_size,
                              hipStream_t stream) {
    const float* x     = (const float*)d_in[0];
    const float* hx    = (const float*)d_in[1];
    const float* cx    = (const float*)d_in[2];
    const float* u     = (const float*)d_in[3];
    const float* W_ih  = (const float*)d_in[4];
    const float* W_hh  = (const float*)d_in[5];
    const float* b_ih  = (const float*)d_in[6];
    const float* b_hh  = (const float*)d_in[7];
    const float* W_dec = (const float*)d_in[8];
    const float* b_dec = (const float*)d_in[9];
    float* out = (float*)d_out;

    dim3 grid(BATCH / 256), block(256);
    lstm_coord_kernel<<<grid, block, 0, stream>>>(
        x, hx, cx, u, W_ih, W_hh, b_ih, b_hh, W_dec, b_dec, out);
}

// Round 2
// 378.578 us; speedup vs baseline: 1.5935x; 1.5935x over previous
//
#include <hip/hip_runtime.h>

constexpr int BATCH = 1048576;
constexpr int H = 20;       // hidden
constexpr int BLK = 256;    // threads per block = batch rows per block
constexpr int RS = 21;      // padded LDS row stride (gcd(21,32)=1 -> conflict-free)
constexpr int TILE = BLK * H;   // 5120 floats per tile

__device__ __forceinline__ float sigmoidf_stable(float z) {
    if (z >= 0.0f) {
        float e = expf(-z);
        return 1.0f / (1.0f + e);
    } else {
        float e = expf(z);
        return e / (1.0f + e);
    }
}

__global__ __launch_bounds__(BLK) void lstm_coord_kernel(
    const float* __restrict__ x,
    const float* __restrict__ hx,
    const float* __restrict__ cx,
    const float* __restrict__ u,
    const float* __restrict__ W_ih,
    const float* __restrict__ W_hh,
    const float* __restrict__ b_ih,
    const float* __restrict__ b_hh,
    const float* __restrict__ W_dec,
    const float* __restrict__ b_dec,
    float* __restrict__ out)
{
    // ---- weights in LDS (uniform-address broadcast reads) ----
    __shared__ float sWih[80 * 2];
    __shared__ float sWhh[80 * H];
    __shared__ float sB[80];        // b_ih + b_hh fused
    __shared__ float sWdec[3 * H];
    __shared__ float sBdec[3];
    // ---- per-block row tiles, padded stride 21 ----
    __shared__ float sH[BLK * RS];
    __shared__ float sC[BLK * RS];

    const int t = threadIdx.x;
    for (int i = t; i < 160; i += BLK)  sWih[i] = W_ih[i];
    for (int i = t; i < 1600; i += BLK) sWhh[i] = W_hh[i];
    if (t < 80) sB[t] = b_ih[t] + b_hh[t];
    if (t < 60) sWdec[t] = W_dec[t];
    if (t < 3)  sBdec[t] = b_dec[t];

    // ---- coalesced global->LDS staging of hx/cx tiles ----
    const size_t base = (size_t)blockIdx.x * TILE;  // float offset of this block's tile
#pragma unroll
    for (int j = 0; j < 5; ++j) {
        const int g = 4 * (t + BLK * j);            // 0..5116, 16B-aligned
        float4 v = *reinterpret_cast<const float4*>(hx + base + g);
#pragma unroll
        for (int e = 0; e < 4; ++e) {
            const int gg = g + e;
            sH[gg + gg / H] = (&v.x)[e];            // r*21+k == g + g/20
        }
        float4 w = *reinterpret_cast<const float4*>(cx + base + g);
#pragma unroll
        for (int e = 0; e < 4; ++e) {
            const int gg = g + e;
            sC[gg + gg / H] = (&w.x)[e];
        }
    }
    __syncthreads();

    const int b = blockIdx.x * BLK + t;

    // per-element scalars (coalesced: 8B + 4B per lane)
    const float2 xv = *reinterpret_cast<const float2*>(x + 2 * (size_t)b);
    const float x0 = xv.x, x1 = xv.y;
    const float uv = u[b];

    // own-row hx into registers (conflict-free: stride 21)
    float hv[H];
    const int row = t * RS;
#pragma unroll
    for (int k = 0; k < H; ++k) hv[k] = sH[row + k];

    // ---- LSTM cell + fused decode accumulation ----
    // NOTE: expression order kept identical to the validated R1 kernel.
    float l0 = sBdec[0], l1 = sBdec[1], l2 = sBdec[2];
#pragma unroll
    for (int q = 0; q < H; ++q) {
        float gi = sB[q]      + x0 * sWih[2 * q]          + x1 * sWih[2 * q + 1];
        float gf = sB[20 + q] + x0 * sWih[2 * (20 + q)]   + x1 * sWih[2 * (20 + q) + 1];
        float gg = sB[40 + q] + x0 * sWih[2 * (40 + q)]   + x1 * sWih[2 * (40 + q) + 1];
        float go = sB[60 + q] + x0 * sWih[2 * (60 + q)]   + x1 * sWih[2 * (60 + q) + 1];
#pragma unroll
        for (int k = 0; k < H; ++k) {
            const float hk = hv[k];
            gi += hk * sWhh[(q)      * H + k];
            gf += hk * sWhh[(20 + q) * H + k];
            gg += hk * sWhh[(40 + q) * H + k];
            go += hk * sWhh[(60 + q) * H + k];
        }
        gi = sigmoidf_stable(gi);
        gf = sigmoidf_stable(gf);
        gg = tanhf(gg);
        go = sigmoidf_stable(go);
        const float cq = gf * sC[row + q] + gi * gg;
        const float hq = go * tanhf(cq);
        sC[row + q] = cq;       // own row only -> no sync needed
        sH[row + q] = hq;       // own row only (hv already in regs)
        l0 += hq * sWdec[q];
        l1 += hq * sWdec[20 + q];
        l2 += hq * sWdec[40 + q];
    }

    // ---- log_softmax + inverse-CDF sample (identical op order to R1) ----
    const float m = fmaxf(fmaxf(l0, l1), l2);
    const float s = expf(l0 - m) + expf(l1 - m) + expf(l2 - m);
    const float lse = m + logf(s);
    const float lp0 = l0 - lse, lp1 = l1 - lse, lp2 = l2 - lse;
    const float p0 = expf(lp0), p1 = expf(lp1), p2 = expf(lp2);
    const float c0 = p0;
    const float c1 = c0 + p1;
    const float c2 = c1 + p2;
    int act = (int)(c0 < uv) + (int)(c1 < uv) + (int)(c2 < uv);
    act = act > 2 ? 2 : act;
    const float slp = (act == 0) ? lp0 : ((act == 1) ? lp1 : lp2);

    out[b] = (float)act;                 // coalesced
    out[(size_t)BATCH + b] = slp;        // coalesced

    __syncthreads();   // all rows of sH/sC finalized

    // ---- coalesced LDS->global stores of h/c tiles ----
    float* hout  = out + 2 * (size_t)BATCH;
    float* cout_ = hout + (size_t)H * BATCH;
#pragma unroll
    for (int j = 0; j < 5; ++j) {
        const int g = 4 * (t + BLK * j);
        float4 v, w;
#pragma unroll
        for (int e = 0; e < 4; ++e) {
            const int gg = g + e;
            (&v.x)[e] = sH[gg + gg / H];
            (&w.x)[e] = sC[gg + gg / H];
        }
        *reinterpret_cast<float4*>(hout  + base + g) = v;
        *reinterpret_cast<float4*>(cout_ + base + g) = w;
    }
}

extern "C" void kernel_launch(void* const* d_in, const int* in_sizes, int n_in,
                              void* d_out, int out_size, void* d_ws, size_t ws_size,
                              hipStream_t stream) {
    const float* x     = (const float*)d_in[0];
    const float* hx    = (const float*)d_in[1];
    const float* cx    = (const float*)d_in[2];
    const float* u     = (const float*)d_in[3];
    const float* W_ih  = (const float*)d_in[4];
    const float* W_hh  = (const float*)d_in[5];
    const float* b_ih  = (const float*)d_in[6];
    const float* b_hh  = (const float*)d_in[7];
    const float* W_dec = (const float*)d_in[8];
    const float* b_dec = (const float*)d_in[9];
    float* out = (float*)d_out;

    dim3 grid(BATCH / BLK), block(BLK);
    lstm_coord_kernel<<<grid, block, 0, stream>>>(
        x, hx, cx, u, W_ih, W_hh, b_ih, b_hh, W_dec, b_dec, out);
}

// Round 3
// 174.350 us; speedup vs baseline: 3.4600x; 2.1714x over previous
//
#include <hip/hip_runtime.h>

constexpr int BATCH = 1048576;
constexpr int H = 20;       // hidden
constexpr int BLK = 256;    // threads per block = batch rows per block
constexpr int RS = 21;      // padded LDS row stride (gcd(21,32)=1 -> conflict-free)
constexpr int TILE = BLK * H;   // 5120 floats per tile

__device__ __forceinline__ float sigmoidf_stable(float z) {
    if (z >= 0.0f) {
        float e = expf(-z);
        return 1.0f / (1.0f + e);
    } else {
        float e = expf(z);
        return e / (1.0f + e);
    }
}

__global__ __launch_bounds__(BLK) void lstm_coord_kernel(
    const float* __restrict__ x,
    const float* __restrict__ hx,
    const float* __restrict__ cx,
    const float* __restrict__ u,
    const float* __restrict__ W_ih,
    const float* __restrict__ W_hh,
    const float* __restrict__ b_ih,
    const float* __restrict__ b_hh,
    const float* __restrict__ W_dec,
    const float* __restrict__ b_dec,
    float* __restrict__ out)
{
    // ---- per-block row tiles, padded stride 21 (NO weight LDS: weights are
    // wave-uniform compile-time-indexed loads -> SMEM/s_load + SGPR operands) ----
    __shared__ float sH[BLK * RS];
    __shared__ float sC[BLK * RS];

    const int t = threadIdx.x;

    // ---- coalesced global->LDS staging of hx/cx tiles ----
    const size_t base = (size_t)blockIdx.x * TILE;  // float offset of this block's tile
#pragma unroll
    for (int j = 0; j < 5; ++j) {
        const int g = 4 * (t + BLK * j);            // 0..5116, 16B-aligned
        float4 v = *reinterpret_cast<const float4*>(hx + base + g);
#pragma unroll
        for (int e = 0; e < 4; ++e) {
            const int gg = g + e;
            sH[gg + gg / H] = (&v.x)[e];            // r*21+k == g + g/20
        }
        float4 w = *reinterpret_cast<const float4*>(cx + base + g);
#pragma unroll
        for (int e = 0; e < 4; ++e) {
            const int gg = g + e;
            sC[gg + gg / H] = (&w.x)[e];
        }
    }
    __syncthreads();

    const int b = blockIdx.x * BLK + t;

    // per-element scalars (coalesced: 8B + 4B per lane)
    const float2 xv = *reinterpret_cast<const float2*>(x + 2 * (size_t)b);
    const float x0 = xv.x, x1 = xv.y;
    const float uv = u[b];

    // own-row hx into registers (conflict-free: stride 21)
    float hv[H];
    const int row = t * RS;
#pragma unroll
    for (int k = 0; k < H; ++k) hv[k] = sH[row + k];

    // ---- LSTM cell + fused decode accumulation ----
    // NOTE: expression order kept identical to the validated R1/R2 kernels.
    // All weight/bias accesses are wave-uniform with constant indices ->
    // compiler scalarizes to s_load; FMAs take the weight as SGPR operand.
    float l0 = b_dec[0], l1 = b_dec[1], l2 = b_dec[2];
#pragma unroll
    for (int q = 0; q < H; ++q) {
        float gi = (b_ih[q]      + b_hh[q])      + x0 * W_ih[2 * q]            + x1 * W_ih[2 * q + 1];
        float gf = (b_ih[20 + q] + b_hh[20 + q]) + x0 * W_ih[2 * (20 + q)]     + x1 * W_ih[2 * (20 + q) + 1];
        float gg = (b_ih[40 + q] + b_hh[40 + q]) + x0 * W_ih[2 * (40 + q)]     + x1 * W_ih[2 * (40 + q) + 1];
        float go = (b_ih[60 + q] + b_hh[60 + q]) + x0 * W_ih[2 * (60 + q)]     + x1 * W_ih[2 * (60 + q) + 1];
#pragma unroll
        for (int k = 0; k < H; ++k) {
            const float hk = hv[k];
            gi += hk * W_hh[(q)      * H + k];
            gf += hk * W_hh[(20 + q) * H + k];
            gg += hk * W_hh[(40 + q) * H + k];
            go += hk * W_hh[(60 + q) * H + k];
        }
        gi = sigmoidf_stable(gi);
        gf = sigmoidf_stable(gf);
        gg = tanhf(gg);
        go = sigmoidf_stable(go);
        const float cq = gf * sC[row + q] + gi * gg;
        const float hq = go * tanhf(cq);
        sC[row + q] = cq;       // own row only -> no sync needed
        sH[row + q] = hq;       // own row only (hv already in regs)
        l0 += hq * W_dec[q];
        l1 += hq * W_dec[20 + q];
        l2 += hq * W_dec[40 + q];
    }

    // ---- log_softmax + inverse-CDF sample (identical op order to R1/R2) ----
    const float m = fmaxf(fmaxf(l0, l1), l2);
    const float s = expf(l0 - m) + expf(l1 - m) + expf(l2 - m);
    const float lse = m + logf(s);
    const float lp0 = l0 - lse, lp1 = l1 - lse, lp2 = l2 - lse;
    const float p0 = expf(lp0), p1 = expf(lp1), p2 = expf(lp2);
    const float c0 = p0;
    const float c1 = c0 + p1;
    const float c2 = c1 + p2;
    int act = (int)(c0 < uv) + (int)(c1 < uv) + (int)(c2 < uv);
    act = act > 2 ? 2 : act;
    const float slp = (act == 0) ? lp0 : ((act == 1) ? lp1 : lp2);

    out[b] = (float)act;                 // coalesced
    out[(size_t)BATCH + b] = slp;        // coalesced

    __syncthreads();   // all rows of sH/sC finalized

    // ---- coalesced LDS->global stores of h/c tiles ----
    float* hout  = out + 2 * (size_t)BATCH;
    float* cout_ = hout + (size_t)H * BATCH;
#pragma unroll
    for (int j = 0; j < 5; ++j) {
        const int g = 4 * (t + BLK * j);
        float4 v, w;
#pragma unroll
        for (int e = 0; e < 4; ++e) {
            const int gg = g + e;
            (&v.x)[e] = sH[gg + gg / H];
            (&w.x)[e] = sC[gg + gg / H];
        }
        *reinterpret_cast<float4*>(hout  + base + g) = v;
        *reinterpret_cast<float4*>(cout_ + base + g) = w;
    }
}

extern "C" void kernel_launch(void* const* d_in, const int* in_sizes, int n_in,
                              void* d_out, int out_size, void* d_ws, size_t ws_size,
                              hipStream_t stream) {
    const float* x     = (const float*)d_in[0];
    const float* hx    = (const float*)d_in[1];
    const float* cx    = (const float*)d_in[2];
    const float* u     = (const float*)d_in[3];
    const float* W_ih  = (const float*)d_in[4];
    const float* W_hh  = (const float*)d_in[5];
    const float* b_ih  = (const float*)d_in[6];
    const float* b_hh  = (const float*)d_in[7];
    const float* W_dec = (const float*)d_in[8];
    const float* b_dec = (const float*)d_in[9];
    float* out = (float*)d_out;

    dim3 grid(BATCH / BLK), block(BLK);
    lstm_coord_kernel<<<grid, block, 0, stream>>>(
        x, hx, cx, u, W_ih, W_hh, b_ih, b_hh, W_dec, b_dec, out);
}